// Round 12
// baseline (669.768 us; speedup 1.0000x reference)
//
#include <hip/hip_runtime.h>
#include <hip/hip_bf16.h>

#define NN 50000
#define HH 128
#define H2 256
#define EE 800000
#define NBUCK 196          // ceil(NN/256)
#define BINCH 4096         // edges per bin-pass block
#define MT 96              // score/xW M-tile (96 rows -> 50.7KB LDS -> 3 blocks/CU)

typedef _Float16 half8 __attribute__((ext_vector_type(8)));
typedef _Float16 half4v __attribute__((ext_vector_type(4)));
typedef float float4v __attribute__((ext_vector_type(4)));

__device__ __forceinline__ float bf2f(unsigned short u) {
  union { unsigned int i; float f; } v; v.i = ((unsigned int)u) << 16; return v.f;
}
__device__ __forceinline__ unsigned short f2bf(float f) {
  union { float f; unsigned int i; } v; v.f = f;
  unsigned int x = v.i;
  unsigned int r = x + 0x7fffu + ((x >> 16) & 1u);   // RNE
  return (unsigned short)(r >> 16);
}

// ---------------- dtype detection (fp32 vs bf16 float tensors) ----------------
__global__ void detect_kernel(const unsigned int* __restrict__ val, int* __restrict__ dt) {
  unsigned int w = val[threadIdx.x];
  unsigned short u = (unsigned short)(w & 0xffff);
  int expf = (u >> 7) & 0xff;
  bool match = ((u >> 15) == 0) && expf >= 0x5A && expf <= 0x7E;
  unsigned long long m = __ballot(match);
  if (threadIdx.x == 0) dt[0] = (__popcll(m) >= 48) ? 1 : 0;
}

// ---------------- merged parameter conversion (14 segments, 1 launch) ----------------
#define NSEG 14
struct ConvSegs {
  const void* s[NSEG];
  void* d[NSEG];
  int n[NSEG];
  int mode[NSEG];      // 0: f32 out, 1: f16 out, 2: f16 out transposed 128x128
  int bstart[NSEG + 1];
};

__global__ __launch_bounds__(256) void convall_kernel(ConvSegs cs, const int* __restrict__ dt) {
  int b = blockIdx.x;
  int seg = 0;
  while (b >= cs.bstart[seg + 1]) ++seg;
  int i = (b - cs.bstart[seg]) * 256 + threadIdx.x;
  if (i >= cs.n[seg]) return;
  float f = dt[0] ? bf2f(((const unsigned short*)cs.s[seg])[i])
                  : ((const float*)cs.s[seg])[i];
  int m = cs.mode[seg];
  if (m == 0) ((float*)cs.d[seg])[i] = f;
  else if (m == 1) ((_Float16*)cs.d[seg])[i] = (_Float16)f;
  else {
    int r = i >> 7, c = i & 127;
    ((_Float16*)cs.d[seg])[c * 128 + r] = (_Float16)f;
  }
}

// ---------------- CSR build: bucket-local ----------------
__global__ __launch_bounds__(256) void bincount_kernel(
    const int* __restrict__ r0, const int* __restrict__ r1,
    int* __restrict__ bcnt, int E) {
  int br = blockIdx.y;
  const int* rows = br ? r1 : r0;
  __shared__ int cnt_s[NBUCK];
  int t = threadIdx.x;
  for (int i = t; i < NBUCK; i += 256) cnt_s[i] = 0;
  __syncthreads();
  int e0 = blockIdx.x * BINCH;
  #pragma unroll
  for (int i = 0; i < 16; ++i) {
    int e = e0 + i * 256 + t;
    if (e < E) atomicAdd(&cnt_s[rows[e] >> 8], 1);
  }
  __syncthreads();
  for (int i = t; i < NBUCK; i += 256) {
    int c = cnt_s[i];
    if (c) atomicAdd(&bcnt[br * NBUCK + i], c);
  }
}

__global__ __launch_bounds__(256) void bscan_kernel(const int* __restrict__ bcnt,
                                                    int* __restrict__ bbase,
                                                    int* __restrict__ gcur) {
  int br = blockIdx.y, t = threadIdx.x;
  __shared__ int s[256];
  int v = (t < NBUCK) ? bcnt[br * NBUCK + t] : 0;
  s[t] = v;
  __syncthreads();
  for (int off = 1; off < 256; off <<= 1) {
    int u = (t >= off) ? s[t - off] : 0;
    __syncthreads();
    s[t] += u;
    __syncthreads();
  }
  int ex = s[t] - v;
  if (t < NBUCK) { bbase[br * NBUCK + t] = ex; gcur[br * NBUCK + t] = ex; }
}

__global__ __launch_bounds__(256) void bin_kernel(
    const int* __restrict__ r0, const int* __restrict__ r1,
    const int* __restrict__ c0, const int* __restrict__ c1,
    const void* __restrict__ v0, const void* __restrict__ v1,
    int* __restrict__ gcur, int2* __restrict__ binned, int E, const int* __restrict__ dt) {
  int br = blockIdx.y;
  const int* rows = br ? r1 : r0;
  const int* cols = br ? c1 : c0;
  const void* vals = br ? v1 : v0;
  int2* bout = binned + (size_t)br * EE;
  int* cur = gcur + br * NBUCK;
  __shared__ int cnt_s[NBUCK];
  __shared__ int base_s[NBUCK];
  int t = threadIdx.x;
  for (int i = t; i < NBUCK; i += 256) cnt_s[i] = 0;
  __syncthreads();
  int e0 = blockIdx.x * BINCH;
  int row[16], col[16], vb[16];
  int cnt = 0;
  bool isb = dt[0] != 0;
  #pragma unroll
  for (int i = 0; i < 16; ++i) {
    int e = e0 + i * 256 + t;
    if (e < E) {
      row[cnt] = rows[e];
      col[cnt] = cols[e];
      float v = isb ? bf2f(((const unsigned short*)vals)[e]) : ((const float*)vals)[e];
      vb[cnt] = __float_as_int(v);
      atomicAdd(&cnt_s[row[cnt] >> 8], 1);
      ++cnt;
    }
  }
  __syncthreads();
  for (int i = t; i < NBUCK; i += 256) {
    int c = cnt_s[i];
    base_s[i] = c ? atomicAdd(&cur[i], c) : 0;
    cnt_s[i] = 0;
  }
  __syncthreads();
  for (int i = 0; i < cnt; ++i) {
    int b = row[i] >> 8;
    int off = atomicAdd(&cnt_s[b], 1);
    bout[base_s[b] + off] = make_int2((row[i] << 16) | col[i], vb[i]);
  }
}

__global__ __launch_bounds__(256) void bucket_kernel(
    const int* __restrict__ bbase, const int2* __restrict__ binned,
    int2* __restrict__ edges, int* __restrict__ rp, int N, int E) {
  int br = blockIdx.y, b = blockIdx.x, t = threadIdx.x;
  const int2* bin = binned + (size_t)br * EE;
  int2* eo = edges + (size_t)br * EE;
  int* r = rp + br * (NN + 1);
  __shared__ int cur[256];
  __shared__ int s[256];
  int base = bbase[br * NBUCK + b];
  int end  = (b + 1 < NBUCK) ? bbase[br * NBUCK + b + 1] : E;
  cur[t] = 0;
  __syncthreads();
  for (int i = base + t; i < end; i += 256)
    atomicAdd(&cur[(((unsigned)bin[i].x) >> 16) & 255], 1);
  __syncthreads();
  int v = cur[t];
  s[t] = v;
  __syncthreads();
  for (int off = 1; off < 256; off <<= 1) {
    int u = (t >= off) ? s[t - off] : 0;
    __syncthreads();
    s[t] += u;
    __syncthreads();
  }
  int ex = base + s[t] - v;
  int row = b * 256 + t;
  if (row < N) r[row] = ex;
  if (b == 0 && t == 0) r[N] = E;
  cur[t] = ex;
  __syncthreads();
  for (int i = base + t; i < end; i += 256) {
    int2 e = bin[i];
    int rl = (((unsigned)e.x) >> 16) & 255;
    int p = atomicAdd(&cur[rl], 1);
    eo[p] = make_int2(e.x & 0xffff, e.y);
  }
}

// ---------------- SpMM: 16-lane group (fp16x8 = 16B/lane) per row, unroll 4 ----------------
// (R9 structure: 4 independent named accumulator banks — measured 61.5 us; do not "improve")
template<int DO_L2>
__global__ __launch_bounds__(256) void spmm_kernel(
    const int* __restrict__ rp, const int2* __restrict__ edges,
    const _Float16* __restrict__ src, size_t sstride, const float* __restrict__ bias,
    _Float16* __restrict__ dst, size_t dstride, int N)
{
  int br = blockIdx.y;
  rp += br * (NN + 1);
  edges += (size_t)br * EE;
  src += br * sstride;
  dst += br * dstride;
  int g = threadIdx.x >> 4;
  int l = threadIdx.x & 15;
  int r = blockIdx.x * 16 + g;
  if (r >= N) return;
  int kb = rp[r], ke = rp[r + 1];
  float a0[8] = {0,0,0,0,0,0,0,0}, a1[8] = {0,0,0,0,0,0,0,0};
  float a2[8] = {0,0,0,0,0,0,0,0}, a3[8] = {0,0,0,0,0,0,0,0};
  int k = kb;
  for (; k + 3 < ke; k += 4) {
    int2 e0 = edges[k], e1 = edges[k + 1], e2 = edges[k + 2], e3 = edges[k + 3];
    half8 s0 = *(const half8*)(src + (size_t)e0.x * HH + l * 8);
    half8 s1 = *(const half8*)(src + (size_t)e1.x * HH + l * 8);
    half8 s2 = *(const half8*)(src + (size_t)e2.x * HH + l * 8);
    half8 s3 = *(const half8*)(src + (size_t)e3.x * HH + l * 8);
    float v0 = __int_as_float(e0.y), v1 = __int_as_float(e1.y);
    float v2 = __int_as_float(e2.y), v3 = __int_as_float(e3.y);
    #pragma unroll
    for (int j = 0; j < 8; ++j) {
      a0[j] = fmaf(v0, (float)s0[j], a0[j]);
      a1[j] = fmaf(v1, (float)s1[j], a1[j]);
      a2[j] = fmaf(v2, (float)s2[j], a2[j]);
      a3[j] = fmaf(v3, (float)s3[j], a3[j]);
    }
  }
  for (; k < ke; ++k) {
    int2 e0 = edges[k];
    half8 s0 = *(const half8*)(src + (size_t)e0.x * HH + l * 8);
    float v0 = __int_as_float(e0.y);
    #pragma unroll
    for (int j = 0; j < 8; ++j) a0[j] = fmaf(v0, (float)s0[j], a0[j]);
  }
  float x[8];
  #pragma unroll
  for (int j = 0; j < 8; ++j)
    x[j] = fmaxf((a0[j] + a1[j]) + (a2[j] + a3[j]) + bias[l * 8 + j], 0.f);
  if (DO_L2) {
    float ss = 0.f;
    #pragma unroll
    for (int j = 0; j < 8; ++j) ss += x[j] * x[j];
    #pragma unroll
    for (int m = 1; m < 16; m <<= 1) ss += __shfl_xor(ss, m, 64);
    float sc = 1.f / fmaxf(sqrtf(ss), 1e-12f);
    #pragma unroll
    for (int j = 0; j < 8; ++j) x[j] *= sc;
  }
  half8 hv;
  #pragma unroll
  for (int j = 0; j < 8; ++j) hv[j] = (_Float16)x[j];
  *(half8*)&dst[(size_t)r * HH + l * 8] = hv;
}

// ---------------- fused score MLP (z=0) + xW GEMM (z=1), 96-row tiles ----------------
// z=0: sacc += relu(relu(x@W1^T+b1)@W2^T+b2)@w3  (h1 96x264 in dynamic LDS = 50.7KB -> 3 blocks/CU)
// z=1: tb = x @ Wt^T  (Wt pre-transposed [n,k])
__global__ __launch_bounds__(256, 3) void score_kernel(
    const _Float16* __restrict__ x, size_t xs,
    const _Float16* __restrict__ w1, const _Float16* __restrict__ w2,
    const float* __restrict__ b1v, const float* __restrict__ b2v, const float* __restrict__ w3v,
    float* __restrict__ S, size_t ss,
    const _Float16* __restrict__ wt, _Float16* __restrict__ tb, int M)
{
  constexpr int HS = H2 + 8;                 // 264 halves
  extern __shared__ _Float16 h1s[];          // MT * HS * 2 = 50688 B
  int br = blockIdx.y;
  x += br * xs;
  const int lane = threadIdx.x & 63, w = threadIdx.x >> 6;
  const int lm = lane & 15, lq = lane >> 4;
  const int m0 = blockIdx.x * MT;

  if (blockIdx.z == 1) {
    // ---- xW path: 96 rows x 128 cols, wave w: m-half (w&1)*48, n-half (w>>1)*64 ----
    tb += br * xs;
    const int wm = (w & 1) * 48, wn = (w >> 1) * 64;
    const _Float16* Abase = x + (size_t)(m0 + wm + lm) * HH + lq * 8;
    const _Float16* Bbase = wt + (size_t)(wn + lm) * HH + lq * 8;
    float4v acc[3][4];
    #pragma unroll
    for (int i = 0; i < 3; ++i)
      #pragma unroll
      for (int j = 0; j < 4; ++j) acc[i][j] = (float4v){0.f, 0.f, 0.f, 0.f};
    #pragma unroll
    for (int k0 = 0; k0 < HH; k0 += 32) {
      half8 ah[3], bh[4];
      #pragma unroll
      for (int mt = 0; mt < 3; ++mt) ah[mt] = *(const half8*)(Abase + (size_t)mt * 16 * HH + k0);
      #pragma unroll
      for (int nt = 0; nt < 4; ++nt) bh[nt] = *(const half8*)(Bbase + (size_t)nt * 16 * HH + k0);
      #pragma unroll
      for (int mt = 0; mt < 3; ++mt)
        #pragma unroll
        for (int nt = 0; nt < 4; ++nt)
          acc[mt][nt] = __builtin_amdgcn_mfma_f32_16x16x32_f16(ah[mt], bh[nt], acc[mt][nt], 0, 0, 0);
    }
    #pragma unroll
    for (int mt = 0; mt < 3; ++mt)
      #pragma unroll
      for (int r = 0; r < 4; ++r) {
        int row = m0 + wm + mt * 16 + lq * 4 + r;
        if (row >= M) continue;
        #pragma unroll
        for (int nt = 0; nt < 4; ++nt)
          tb[(size_t)row * HH + wn + nt * 16 + lm] = (_Float16)acc[mt][nt][r];
      }
    return;
  }

  // ---- score path: each wave owns 64 n-cols, all 96 rows (6x4 acc) ----
  S += br * ss;
  const int wn = w * 64;
  {
    const _Float16* Abase = x + (size_t)(m0 + lm) * HH + lq * 8;
    const _Float16* Bbase = w1 + (size_t)(wn + lm) * HH + lq * 8;
    float4v acc[6][4];
    #pragma unroll
    for (int i = 0; i < 6; ++i)
      #pragma unroll
      for (int j = 0; j < 4; ++j) acc[i][j] = (float4v){0.f, 0.f, 0.f, 0.f};
    #pragma unroll
    for (int k0 = 0; k0 < HH; k0 += 32) {
      half8 ah[6], bh[4];
      #pragma unroll
      for (int mt = 0; mt < 6; ++mt) ah[mt] = *(const half8*)(Abase + (size_t)mt * 16 * HH + k0);
      #pragma unroll
      for (int nt = 0; nt < 4; ++nt) bh[nt] = *(const half8*)(Bbase + (size_t)nt * 16 * HH + k0);
      #pragma unroll
      for (int mt = 0; mt < 6; ++mt)
        #pragma unroll
        for (int nt = 0; nt < 4; ++nt)
          acc[mt][nt] = __builtin_amdgcn_mfma_f32_16x16x32_f16(ah[mt], bh[nt], acc[mt][nt], 0, 0, 0);
    }
    float bv[4];
    #pragma unroll
    for (int nt = 0; nt < 4; ++nt) bv[nt] = b1v[wn + nt * 16 + lm];
    #pragma unroll
    for (int mt = 0; mt < 6; ++mt)
      #pragma unroll
      for (int r = 0; r < 4; ++r) {
        int rowl = mt * 16 + lq * 4 + r;
        #pragma unroll
        for (int nt = 0; nt < 4; ++nt)
          h1s[rowl * HS + wn + nt * 16 + lm] = (_Float16)fmaxf(acc[mt][nt][r] + bv[nt], 0.f);
      }
  }
  __syncthreads();
  {
    const _Float16* Bbase = w2 + (size_t)(wn + lm) * H2 + lq * 8;
    float4v acc[6][4];
    #pragma unroll
    for (int i = 0; i < 6; ++i)
      #pragma unroll
      for (int j = 0; j < 4; ++j) acc[i][j] = (float4v){0.f, 0.f, 0.f, 0.f};
    #pragma unroll
    for (int k0 = 0; k0 < H2; k0 += 32) {
      half8 ah[6], bh[4];
      #pragma unroll
      for (int mt = 0; mt < 6; ++mt)
        ah[mt] = *(const half8*)&h1s[(mt * 16 + lm) * HS + k0 + lq * 8];
      #pragma unroll
      for (int nt = 0; nt < 4; ++nt) bh[nt] = *(const half8*)(Bbase + (size_t)nt * 16 * H2 + k0);
      #pragma unroll
      for (int mt = 0; mt < 6; ++mt)
        #pragma unroll
        for (int nt = 0; nt < 4; ++nt)
          acc[mt][nt] = __builtin_amdgcn_mfma_f32_16x16x32_f16(ah[mt], bh[nt], acc[mt][nt], 0, 0, 0);
    }
    float bv[4], wv[4];
    #pragma unroll
    for (int nt = 0; nt < 4; ++nt) {
      int col = wn + nt * 16 + lm;
      bv[nt] = b2v[col]; wv[nt] = w3v[col];
    }
    #pragma unroll
    for (int mt = 0; mt < 6; ++mt)
      #pragma unroll
      for (int r = 0; r < 4; ++r) {
        float p = 0.f;
        #pragma unroll
        for (int nt = 0; nt < 4; ++nt)
          p += fmaxf(acc[mt][nt][r] + bv[nt], 0.f) * wv[nt];
        p += __shfl_xor(p, 1, 64);
        p += __shfl_xor(p, 2, 64);
        p += __shfl_xor(p, 4, 64);
        p += __shfl_xor(p, 8, 64);
        if (lm == 0) {
          int row = m0 + mt * 16 + lq * 4 + r;
          if (row < M) atomicAdd(&S[row], p);
        }
      }
  }
}

__global__ void final_kernel(const float* __restrict__ s_in, const float* __restrict__ s_out,
                             const float* __restrict__ b3, void* __restrict__ out, int N,
                             const int* __restrict__ dt) {
  int i = blockIdx.x * 256 + threadIdx.x;
  if (i >= N) return;
  float b = 4.f * b3[0];
  float v = (s_in[i] + b) * (s_out[i] + b);
  if (dt[0]) ((unsigned short*)out)[i] = f2bf(v);
  else       ((float*)out)[i] = v;
}

extern "C" void kernel_launch(void* const* d_in, const int* in_sizes, int n_in,
                              void* d_out, int out_size, void* d_ws, size_t ws_size,
                              hipStream_t stream) {
  const int N = NN, E = EE;

  char* ws = (char*)d_ws;
  size_t o = 0;
  auto alloc = [&](size_t bytes) -> void* {
    void* p = ws + o;
    o = (o + bytes + 255) & ~(size_t)255;
    return p;
  };

  int* dt = (int*)alloc(16);
  float* bc[4]; float* l1b; float* l2b; float* w3f; float* l3b;
  for (int i = 0; i < 4; ++i) bc[i] = (float*)alloc(HH * 4);
  l1b = (float*)alloc(H2 * 4);
  l2b = (float*)alloc(H2 * 4);
  w3f = (float*)alloc(H2 * 4);
  l3b = (float*)alloc(4);
  _Float16* l1w_h = (_Float16*)alloc(H2 * HH * 2);
  _Float16* l2w_h = (_Float16*)alloc(H2 * H2 * 2);
  _Float16* Wt_h[3];
  for (int i = 0; i < 3; ++i) Wt_h[i] = (_Float16*)alloc(HH * HH * 2);
  _Float16* w1_h = (_Float16*)alloc((size_t)N * HH * 2);

  const int NP = N + 128;
  const size_t XS = (size_t)NP * HH;
  int* rp    = (int*)alloc(2 * (size_t)(N + 1) * 4);
  int* bcnt  = (int*)alloc(2 * NBUCK * 4);
  int* bbase = (int*)alloc(2 * NBUCK * 4);
  int* gcur  = (int*)alloc(2 * NBUCK * 4);
  int2* binned = (int2*)alloc(2 * (size_t)E * 8);
  int2* edges  = (int2*)alloc(2 * (size_t)E * 8);
  _Float16* x_h  = (_Float16*)alloc(2 * XS * 2);
  _Float16* tb_h = (_Float16*)alloc(2 * XS * 2);
  float* sacc = (float*)alloc(2 * (size_t)N * 4);

  dim3 blk(256);
  detect_kernel<<<1, 64, 0, stream>>>((const unsigned int*)d_in[2], dt);

  // merged conversions
  ConvSegs cs;
  const void* srcs[NSEG] = {d_in[7], d_in[9], d_in[11], d_in[13], d_in[15], d_in[17],
                            d_in[18], d_in[19], d_in[14], d_in[16], d_in[8], d_in[10],
                            d_in[12], d_in[6]};
  void* dsts[NSEG] = {bc[0], bc[1], bc[2], bc[3], l1b, l2b, w3f, l3b,
                      l1w_h, l2w_h, Wt_h[0], Wt_h[1], Wt_h[2], w1_h};
  int ns[NSEG] = {HH, HH, HH, HH, H2, H2, H2, 1,
                  H2 * HH, H2 * H2, HH * HH, HH * HH, HH * HH, N * HH};
  int ms[NSEG] = {0, 0, 0, 0, 0, 0, 0, 0, 1, 1, 2, 2, 2, 1};
  int btot = 0;
  for (int i = 0; i < NSEG; ++i) {
    cs.s[i] = srcs[i]; cs.d[i] = dsts[i]; cs.n[i] = ns[i]; cs.mode[i] = ms[i];
    cs.bstart[i] = btot;
    btot += (ns[i] + 255) / 256;
  }
  cs.bstart[NSEG] = btot;
  convall_kernel<<<btot, blk, 0, stream>>>(cs, dt);

  hipMemsetAsync(sacc, 0, 2 * (size_t)N * 4, stream);
  hipMemsetAsync(bcnt, 0, 2 * NBUCK * 4, stream);

  int gx  = (N + MT - 1) / MT;   // 96-row tiles
  int sg  = (N + 15) / 16;
  int bg  = (E + BINCH - 1) / BINCH;
  const size_t SCORE_LDS = MT * (H2 + 8) * sizeof(_Float16);   // 50688 B dynamic

  // ---- CSR build, both branches in parallel ----
  bincount_kernel<<<dim3(bg, 2), blk, 0, stream>>>((const int*)d_in[0], (const int*)d_in[3], bcnt, E);
  bscan_kernel<<<dim3(1, 2), blk, 0, stream>>>(bcnt, bbase, gcur);
  bin_kernel<<<dim3(bg, 2), blk, 0, stream>>>(
      (const int*)d_in[0], (const int*)d_in[3], (const int*)d_in[1], (const int*)d_in[4],
      d_in[2], d_in[5], gcur, binned, E, dt);
  bucket_kernel<<<dim3(NBUCK, 2), blk, 0, stream>>>(bbase, binned, edges, rp, N, E);

  // ---- GNN pipeline, both branches batched ----
  spmm_kernel<1><<<dim3(sg, 2), blk, 0, stream>>>(rp, edges, w1_h, 0, bc[0], x_h, XS, N);

  for (int layer = 0; ; ++layer) {
    int zdim = (layer == 3) ? 1 : 2;
    score_kernel<<<dim3(gx, 2, zdim), blk, SCORE_LDS, stream>>>(
        x_h, XS, l1w_h, l2w_h, l1b, l2b, w3f, sacc, (size_t)N,
        (layer == 3) ? nullptr : Wt_h[layer], tb_h, N);
    if (layer == 3) break;
    if (layer < 2)
      spmm_kernel<1><<<dim3(sg, 2), blk, 0, stream>>>(rp, edges, tb_h, XS, bc[layer + 1], x_h, XS, N);
    else
      spmm_kernel<0><<<dim3(sg, 2), blk, 0, stream>>>(rp, edges, tb_h, XS, bc[3], x_h, XS, N);
  }
  final_kernel<<<(N + 255) / 256, blk, 0, stream>>>(sacc, sacc + N, l3b, d_out, N, dt);
}

// Round 13
// 642.561 us; speedup vs baseline: 1.0423x; 1.0423x over previous
//
#include <hip/hip_runtime.h>
#include <hip/hip_bf16.h>

#define NN 50000
#define HH 128
#define H2 256
#define EE 800000
#define NBUCK 196          // ceil(NN/256)
#define BINCH 4096         // edges per bin-pass block
#define MT 96              // score/xW M-tile
#define XST 136            // staged-x LDS row stride (halves): 128 + 8 pad (2-way alias = free)

typedef _Float16 half8 __attribute__((ext_vector_type(8)));
typedef _Float16 half4v __attribute__((ext_vector_type(4)));
typedef float float4v __attribute__((ext_vector_type(4)));

__device__ __forceinline__ float bf2f(unsigned short u) {
  union { unsigned int i; float f; } v; v.i = ((unsigned int)u) << 16; return v.f;
}
__device__ __forceinline__ unsigned short f2bf(float f) {
  union { float f; unsigned int i; } v; v.f = f;
  unsigned int x = v.i;
  unsigned int r = x + 0x7fffu + ((x >> 16) & 1u);   // RNE
  return (unsigned short)(r >> 16);
}

// ---------------- dtype detection (fp32 vs bf16 float tensors) ----------------
__global__ void detect_kernel(const unsigned int* __restrict__ val, int* __restrict__ dt) {
  unsigned int w = val[threadIdx.x];
  unsigned short u = (unsigned short)(w & 0xffff);
  int expf = (u >> 7) & 0xff;
  bool match = ((u >> 15) == 0) && expf >= 0x5A && expf <= 0x7E;
  unsigned long long m = __ballot(match);
  if (threadIdx.x == 0) dt[0] = (__popcll(m) >= 48) ? 1 : 0;
}

// ---------------- merged parameter conversion (14 segments, 1 launch) ----------------
#define NSEG 14
struct ConvSegs {
  const void* s[NSEG];
  void* d[NSEG];
  int n[NSEG];
  int mode[NSEG];      // 0: f32 out, 1: f16 out, 2: f16 out transposed 128x128
  int bstart[NSEG + 1];
};

__global__ __launch_bounds__(256) void convall_kernel(ConvSegs cs, const int* __restrict__ dt) {
  int b = blockIdx.x;
  int seg = 0;
  while (b >= cs.bstart[seg + 1]) ++seg;
  int i = (b - cs.bstart[seg]) * 256 + threadIdx.x;
  if (i >= cs.n[seg]) return;
  float f = dt[0] ? bf2f(((const unsigned short*)cs.s[seg])[i])
                  : ((const float*)cs.s[seg])[i];
  int m = cs.mode[seg];
  if (m == 0) ((float*)cs.d[seg])[i] = f;
  else if (m == 1) ((_Float16*)cs.d[seg])[i] = (_Float16)f;
  else {
    int r = i >> 7, c = i & 127;
    ((_Float16*)cs.d[seg])[c * 128 + r] = (_Float16)f;
  }
}

// ---------------- CSR build: bucket-local ----------------
__global__ __launch_bounds__(256) void bincount_kernel(
    const int* __restrict__ r0, const int* __restrict__ r1,
    int* __restrict__ bcnt, int E) {
  int br = blockIdx.y;
  const int* rows = br ? r1 : r0;
  __shared__ int cnt_s[NBUCK];
  int t = threadIdx.x;
  for (int i = t; i < NBUCK; i += 256) cnt_s[i] = 0;
  __syncthreads();
  int e0 = blockIdx.x * BINCH;
  #pragma unroll
  for (int i = 0; i < 16; ++i) {
    int e = e0 + i * 256 + t;
    if (e < E) atomicAdd(&cnt_s[rows[e] >> 8], 1);
  }
  __syncthreads();
  for (int i = t; i < NBUCK; i += 256) {
    int c = cnt_s[i];
    if (c) atomicAdd(&bcnt[br * NBUCK + i], c);
  }
}

__global__ __launch_bounds__(256) void bscan_kernel(const int* __restrict__ bcnt,
                                                    int* __restrict__ bbase,
                                                    int* __restrict__ gcur) {
  int br = blockIdx.y, t = threadIdx.x;
  __shared__ int s[256];
  int v = (t < NBUCK) ? bcnt[br * NBUCK + t] : 0;
  s[t] = v;
  __syncthreads();
  for (int off = 1; off < 256; off <<= 1) {
    int u = (t >= off) ? s[t - off] : 0;
    __syncthreads();
    s[t] += u;
    __syncthreads();
  }
  int ex = s[t] - v;
  if (t < NBUCK) { bbase[br * NBUCK + t] = ex; gcur[br * NBUCK + t] = ex; }
}

__global__ __launch_bounds__(256) void bin_kernel(
    const int* __restrict__ r0, const int* __restrict__ r1,
    const int* __restrict__ c0, const int* __restrict__ c1,
    const void* __restrict__ v0, const void* __restrict__ v1,
    int* __restrict__ gcur, int2* __restrict__ binned, int E, const int* __restrict__ dt) {
  int br = blockIdx.y;
  const int* rows = br ? r1 : r0;
  const int* cols = br ? c1 : c0;
  const void* vals = br ? v1 : v0;
  int2* bout = binned + (size_t)br * EE;
  int* cur = gcur + br * NBUCK;
  __shared__ int cnt_s[NBUCK];
  __shared__ int base_s[NBUCK];
  int t = threadIdx.x;
  for (int i = t; i < NBUCK; i += 256) cnt_s[i] = 0;
  __syncthreads();
  int e0 = blockIdx.x * BINCH;
  int row[16], col[16], vb[16];
  int cnt = 0;
  bool isb = dt[0] != 0;
  #pragma unroll
  for (int i = 0; i < 16; ++i) {
    int e = e0 + i * 256 + t;
    if (e < E) {
      row[cnt] = rows[e];
      col[cnt] = cols[e];
      float v = isb ? bf2f(((const unsigned short*)vals)[e]) : ((const float*)vals)[e];
      vb[cnt] = __float_as_int(v);
      atomicAdd(&cnt_s[row[cnt] >> 8], 1);
      ++cnt;
    }
  }
  __syncthreads();
  for (int i = t; i < NBUCK; i += 256) {
    int c = cnt_s[i];
    base_s[i] = c ? atomicAdd(&cur[i], c) : 0;
    cnt_s[i] = 0;
  }
  __syncthreads();
  for (int i = 0; i < cnt; ++i) {
    int b = row[i] >> 8;
    int off = atomicAdd(&cnt_s[b], 1);
    bout[base_s[b] + off] = make_int2((row[i] << 16) | col[i], vb[i]);
  }
}

__global__ __launch_bounds__(256) void bucket_kernel(
    const int* __restrict__ bbase, const int2* __restrict__ binned,
    int2* __restrict__ edges, int* __restrict__ rp, int N, int E) {
  int br = blockIdx.y, b = blockIdx.x, t = threadIdx.x;
  const int2* bin = binned + (size_t)br * EE;
  int2* eo = edges + (size_t)br * EE;
  int* r = rp + br * (NN + 1);
  __shared__ int cur[256];
  __shared__ int s[256];
  int base = bbase[br * NBUCK + b];
  int end  = (b + 1 < NBUCK) ? bbase[br * NBUCK + b + 1] : E;
  cur[t] = 0;
  __syncthreads();
  for (int i = base + t; i < end; i += 256)
    atomicAdd(&cur[(((unsigned)bin[i].x) >> 16) & 255], 1);
  __syncthreads();
  int v = cur[t];
  s[t] = v;
  __syncthreads();
  for (int off = 1; off < 256; off <<= 1) {
    int u = (t >= off) ? s[t - off] : 0;
    __syncthreads();
    s[t] += u;
    __syncthreads();
  }
  int ex = base + s[t] - v;
  int row = b * 256 + t;
  if (row < N) r[row] = ex;
  if (b == 0 && t == 0) r[N] = E;
  cur[t] = ex;
  __syncthreads();
  for (int i = base + t; i < end; i += 256) {
    int2 e = bin[i];
    int rl = (((unsigned)e.x) >> 16) & 255;
    int p = atomicAdd(&cur[rl], 1);
    eo[p] = make_int2(e.x & 0xffff, e.y);
  }
}

// ---------------- SpMM: 16-lane group (fp16x8 = 16B/lane) per row, unroll 4 ----------------
// (R9 structure: 4 independent named accumulator banks — measured 61.5 us; do not "improve")
template<int DO_L2>
__global__ __launch_bounds__(256) void spmm_kernel(
    const int* __restrict__ rp, const int2* __restrict__ edges,
    const _Float16* __restrict__ src, size_t sstride, const float* __restrict__ bias,
    _Float16* __restrict__ dst, size_t dstride, int N)
{
  int br = blockIdx.y;
  rp += br * (NN + 1);
  edges += (size_t)br * EE;
  src += br * sstride;
  dst += br * dstride;
  int g = threadIdx.x >> 4;
  int l = threadIdx.x & 15;
  int r = blockIdx.x * 16 + g;
  if (r >= N) return;
  int kb = rp[r], ke = rp[r + 1];
  float a0[8] = {0,0,0,0,0,0,0,0}, a1[8] = {0,0,0,0,0,0,0,0};
  float a2[8] = {0,0,0,0,0,0,0,0}, a3[8] = {0,0,0,0,0,0,0,0};
  int k = kb;
  for (; k + 3 < ke; k += 4) {
    int2 e0 = edges[k], e1 = edges[k + 1], e2 = edges[k + 2], e3 = edges[k + 3];
    half8 s0 = *(const half8*)(src + (size_t)e0.x * HH + l * 8);
    half8 s1 = *(const half8*)(src + (size_t)e1.x * HH + l * 8);
    half8 s2 = *(const half8*)(src + (size_t)e2.x * HH + l * 8);
    half8 s3 = *(const half8*)(src + (size_t)e3.x * HH + l * 8);
    float v0 = __int_as_float(e0.y), v1 = __int_as_float(e1.y);
    float v2 = __int_as_float(e2.y), v3 = __int_as_float(e3.y);
    #pragma unroll
    for (int j = 0; j < 8; ++j) {
      a0[j] = fmaf(v0, (float)s0[j], a0[j]);
      a1[j] = fmaf(v1, (float)s1[j], a1[j]);
      a2[j] = fmaf(v2, (float)s2[j], a2[j]);
      a3[j] = fmaf(v3, (float)s3[j], a3[j]);
    }
  }
  for (; k < ke; ++k) {
    int2 e0 = edges[k];
    half8 s0 = *(const half8*)(src + (size_t)e0.x * HH + l * 8);
    float v0 = __int_as_float(e0.y);
    #pragma unroll
    for (int j = 0; j < 8; ++j) a0[j] = fmaf(v0, (float)s0[j], a0[j]);
  }
  float x[8];
  #pragma unroll
  for (int j = 0; j < 8; ++j)
    x[j] = fmaxf((a0[j] + a1[j]) + (a2[j] + a3[j]) + bias[l * 8 + j], 0.f);
  if (DO_L2) {
    float ss = 0.f;
    #pragma unroll
    for (int j = 0; j < 8; ++j) ss += x[j] * x[j];
    #pragma unroll
    for (int m = 1; m < 16; m <<= 1) ss += __shfl_xor(ss, m, 64);
    float sc = 1.f / fmaxf(sqrtf(ss), 1e-12f);
    #pragma unroll
    for (int j = 0; j < 8; ++j) x[j] *= sc;
  }
  half8 hv;
  #pragma unroll
  for (int j = 0; j < 8; ++j) hv[j] = (_Float16)x[j];
  *(half8*)&dst[(size_t)r * HH + l * 8] = hv;
}

// ---------------- fused score MLP (z=0) + xW GEMM (z=1), 96-row tiles ----------------
// x tile burst-staged to LDS first (streaming, coalesced) -> A-fragments via ds_read_b128.
// z=0: sacc += relu(relu(x@W1^T+b1)@W2^T+b2)@w3  (h1 96x264 in LDS)
// z=1: tb = x @ Wt^T  (Wt pre-transposed [n,k])
__global__ __launch_bounds__(256, 2) void score_kernel(
    const _Float16* __restrict__ x, size_t xs,
    const _Float16* __restrict__ w1, const _Float16* __restrict__ w2,
    const float* __restrict__ b1v, const float* __restrict__ b2v, const float* __restrict__ w3v,
    float* __restrict__ S, size_t ss,
    const _Float16* __restrict__ wt, _Float16* __restrict__ tb, int M)
{
  constexpr int HS = H2 + 8;                 // 264 halves
  extern __shared__ _Float16 smem[];         // [MT*XST staged x][MT*HS h1] = 26112+50688 B
  _Float16* xls = smem;
  _Float16* h1s = smem + MT * XST;
  int br = blockIdx.y;
  x += br * xs;
  const int lane = threadIdx.x & 63, w = threadIdx.x >> 6;
  const int lm = lane & 15, lq = lane >> 4;
  const int m0 = blockIdx.x * MT;

  // ---- stage x tile (MT x 128 fp16) into LDS: 6 independent uint4 per thread ----
  {
    const uint4* xg = (const uint4*)(x + (size_t)m0 * HH);
    #pragma unroll
    for (int i = 0; i < 6; ++i) {
      int idx = threadIdx.x + i * 256;       // 0..1535
      int row = idx >> 4, cq = idx & 15;     // 16 uint4 per 128-half row
      uint4 v = xg[(size_t)row * 16 + cq];
      *(uint4*)&xls[row * XST + cq * 8] = v;
    }
  }
  __syncthreads();

  if (blockIdx.z == 1) {
    // ---- xW path: 96 rows x 128 cols, wave w: m-half (w&1)*48, n-half (w>>1)*64 ----
    tb += br * xs;
    const int wm = (w & 1) * 48, wn = (w >> 1) * 64;
    const _Float16* Bbase = wt + (size_t)(wn + lm) * HH + lq * 8;
    float4v acc[3][4];
    #pragma unroll
    for (int i = 0; i < 3; ++i)
      #pragma unroll
      for (int j = 0; j < 4; ++j) acc[i][j] = (float4v){0.f, 0.f, 0.f, 0.f};
    #pragma unroll
    for (int k0 = 0; k0 < HH; k0 += 32) {
      half8 ah[3], bh[4];
      #pragma unroll
      for (int mt = 0; mt < 3; ++mt)
        ah[mt] = *(const half8*)&xls[(wm + mt * 16 + lm) * XST + k0 + lq * 8];
      #pragma unroll
      for (int nt = 0; nt < 4; ++nt) bh[nt] = *(const half8*)(Bbase + (size_t)nt * 16 * HH + k0);
      #pragma unroll
      for (int mt = 0; mt < 3; ++mt)
        #pragma unroll
        for (int nt = 0; nt < 4; ++nt)
          acc[mt][nt] = __builtin_amdgcn_mfma_f32_16x16x32_f16(ah[mt], bh[nt], acc[mt][nt], 0, 0, 0);
    }
    #pragma unroll
    for (int mt = 0; mt < 3; ++mt)
      #pragma unroll
      for (int r = 0; r < 4; ++r) {
        int row = m0 + wm + mt * 16 + lq * 4 + r;
        if (row >= M) continue;
        #pragma unroll
        for (int nt = 0; nt < 4; ++nt)
          tb[(size_t)row * HH + wn + nt * 16 + lm] = (_Float16)acc[mt][nt][r];
      }
    return;
  }

  // ---- score path: each wave owns 64 n-cols, all 96 rows (6x4 acc) ----
  S += br * ss;
  const int wn = w * 64;
  {
    const _Float16* Bbase = w1 + (size_t)(wn + lm) * HH + lq * 8;
    float4v acc[6][4];
    #pragma unroll
    for (int i = 0; i < 6; ++i)
      #pragma unroll
      for (int j = 0; j < 4; ++j) acc[i][j] = (float4v){0.f, 0.f, 0.f, 0.f};
    #pragma unroll
    for (int k0 = 0; k0 < HH; k0 += 32) {
      half8 ah[6], bh[4];
      #pragma unroll
      for (int mt = 0; mt < 6; ++mt)
        ah[mt] = *(const half8*)&xls[(mt * 16 + lm) * XST + k0 + lq * 8];
      #pragma unroll
      for (int nt = 0; nt < 4; ++nt) bh[nt] = *(const half8*)(Bbase + (size_t)nt * 16 * HH + k0);
      #pragma unroll
      for (int mt = 0; mt < 6; ++mt)
        #pragma unroll
        for (int nt = 0; nt < 4; ++nt)
          acc[mt][nt] = __builtin_amdgcn_mfma_f32_16x16x32_f16(ah[mt], bh[nt], acc[mt][nt], 0, 0, 0);
    }
    float bv[4];
    #pragma unroll
    for (int nt = 0; nt < 4; ++nt) bv[nt] = b1v[wn + nt * 16 + lm];
    #pragma unroll
    for (int mt = 0; mt < 6; ++mt)
      #pragma unroll
      for (int r = 0; r < 4; ++r) {
        int rowl = mt * 16 + lq * 4 + r;
        #pragma unroll
        for (int nt = 0; nt < 4; ++nt)
          h1s[rowl * HS + wn + nt * 16 + lm] = (_Float16)fmaxf(acc[mt][nt][r] + bv[nt], 0.f);
      }
  }
  __syncthreads();
  {
    const _Float16* Bbase = w2 + (size_t)(wn + lm) * H2 + lq * 8;
    float4v acc[6][4];
    #pragma unroll
    for (int i = 0; i < 6; ++i)
      #pragma unroll
      for (int j = 0; j < 4; ++j) acc[i][j] = (float4v){0.f, 0.f, 0.f, 0.f};
    #pragma unroll
    for (int k0 = 0; k0 < H2; k0 += 32) {
      half8 ah[6], bh[4];
      #pragma unroll
      for (int mt = 0; mt < 6; ++mt)
        ah[mt] = *(const half8*)&h1s[(mt * 16 + lm) * HS + k0 + lq * 8];
      #pragma unroll
      for (int nt = 0; nt < 4; ++nt) bh[nt] = *(const half8*)(Bbase + (size_t)nt * 16 * H2 + k0);
      #pragma unroll
      for (int mt = 0; mt < 6; ++mt)
        #pragma unroll
        for (int nt = 0; nt < 4; ++nt)
          acc[mt][nt] = __builtin_amdgcn_mfma_f32_16x16x32_f16(ah[mt], bh[nt], acc[mt][nt], 0, 0, 0);
    }
    float bv[4], wv[4];
    #pragma unroll
    for (int nt = 0; nt < 4; ++nt) {
      int col = wn + nt * 16 + lm;
      bv[nt] = b2v[col]; wv[nt] = w3v[col];
    }
    #pragma unroll
    for (int mt = 0; mt < 6; ++mt)
      #pragma unroll
      for (int r = 0; r < 4; ++r) {
        float p = 0.f;
        #pragma unroll
        for (int nt = 0; nt < 4; ++nt)
          p += fmaxf(acc[mt][nt][r] + bv[nt], 0.f) * wv[nt];
        p += __shfl_xor(p, 1, 64);
        p += __shfl_xor(p, 2, 64);
        p += __shfl_xor(p, 4, 64);
        p += __shfl_xor(p, 8, 64);
        if (lm == 0) {
          int row = m0 + mt * 16 + lq * 4 + r;
          if (row < M) atomicAdd(&S[row], p);
        }
      }
  }
}

__global__ void final_kernel(const float* __restrict__ s_in, const float* __restrict__ s_out,
                             const float* __restrict__ b3, void* __restrict__ out, int N,
                             const int* __restrict__ dt) {
  int i = blockIdx.x * 256 + threadIdx.x;
  if (i >= N) return;
  float b = 4.f * b3[0];
  float v = (s_in[i] + b) * (s_out[i] + b);
  if (dt[0]) ((unsigned short*)out)[i] = f2bf(v);
  else       ((float*)out)[i] = v;
}

extern "C" void kernel_launch(void* const* d_in, const int* in_sizes, int n_in,
                              void* d_out, int out_size, void* d_ws, size_t ws_size,
                              hipStream_t stream) {
  const int N = NN, E = EE;

  char* ws = (char*)d_ws;
  size_t o = 0;
  auto alloc = [&](size_t bytes) -> void* {
    void* p = ws + o;
    o = (o + bytes + 255) & ~(size_t)255;
    return p;
  };

  int* dt = (int*)alloc(16);
  float* bc[4]; float* l1b; float* l2b; float* w3f; float* l3b;
  for (int i = 0; i < 4; ++i) bc[i] = (float*)alloc(HH * 4);
  l1b = (float*)alloc(H2 * 4);
  l2b = (float*)alloc(H2 * 4);
  w3f = (float*)alloc(H2 * 4);
  l3b = (float*)alloc(4);
  _Float16* l1w_h = (_Float16*)alloc(H2 * HH * 2);
  _Float16* l2w_h = (_Float16*)alloc(H2 * H2 * 2);
  _Float16* Wt_h[3];
  for (int i = 0; i < 3; ++i) Wt_h[i] = (_Float16*)alloc(HH * HH * 2);
  _Float16* w1_h = (_Float16*)alloc((size_t)N * HH * 2);

  const int NP = N + 128;
  const size_t XS = (size_t)NP * HH;
  int* rp    = (int*)alloc(2 * (size_t)(N + 1) * 4);
  int* bcnt  = (int*)alloc(2 * NBUCK * 4);
  int* bbase = (int*)alloc(2 * NBUCK * 4);
  int* gcur  = (int*)alloc(2 * NBUCK * 4);
  int2* binned = (int2*)alloc(2 * (size_t)E * 8);
  int2* edges  = (int2*)alloc(2 * (size_t)E * 8);
  _Float16* x_h  = (_Float16*)alloc(2 * XS * 2);
  _Float16* tb_h = (_Float16*)alloc(2 * XS * 2);
  float* sacc = (float*)alloc(2 * (size_t)N * 4);

  dim3 blk(256);
  detect_kernel<<<1, 64, 0, stream>>>((const unsigned int*)d_in[2], dt);

  // merged conversions
  ConvSegs cs;
  const void* srcs[NSEG] = {d_in[7], d_in[9], d_in[11], d_in[13], d_in[15], d_in[17],
                            d_in[18], d_in[19], d_in[14], d_in[16], d_in[8], d_in[10],
                            d_in[12], d_in[6]};
  void* dsts[NSEG] = {bc[0], bc[1], bc[2], bc[3], l1b, l2b, w3f, l3b,
                      l1w_h, l2w_h, Wt_h[0], Wt_h[1], Wt_h[2], w1_h};
  int ns[NSEG] = {HH, HH, HH, HH, H2, H2, H2, 1,
                  H2 * HH, H2 * H2, HH * HH, HH * HH, HH * HH, N * HH};
  int ms[NSEG] = {0, 0, 0, 0, 0, 0, 0, 0, 1, 1, 2, 2, 2, 1};
  int btot = 0;
  for (int i = 0; i < NSEG; ++i) {
    cs.s[i] = srcs[i]; cs.d[i] = dsts[i]; cs.n[i] = ns[i]; cs.mode[i] = ms[i];
    cs.bstart[i] = btot;
    btot += (ns[i] + 255) / 256;
  }
  cs.bstart[NSEG] = btot;
  convall_kernel<<<btot, blk, 0, stream>>>(cs, dt);

  hipMemsetAsync(sacc, 0, 2 * (size_t)N * 4, stream);
  hipMemsetAsync(bcnt, 0, 2 * NBUCK * 4, stream);

  int gx  = (N + MT - 1) / MT;   // 96-row tiles
  int sg  = (N + 15) / 16;
  int bg  = (E + BINCH - 1) / BINCH;
  const size_t SCORE_LDS = (MT * XST + MT * (H2 + 8)) * sizeof(_Float16);   // 76800 B

  // ---- CSR build, both branches in parallel ----
  bincount_kernel<<<dim3(bg, 2), blk, 0, stream>>>((const int*)d_in[0], (const int*)d_in[3], bcnt, E);
  bscan_kernel<<<dim3(1, 2), blk, 0, stream>>>(bcnt, bbase, gcur);
  bin_kernel<<<dim3(bg, 2), blk, 0, stream>>>(
      (const int*)d_in[0], (const int*)d_in[3], (const int*)d_in[1], (const int*)d_in[4],
      d_in[2], d_in[5], gcur, binned, E, dt);
  bucket_kernel<<<dim3(NBUCK, 2), blk, 0, stream>>>(bbase, binned, edges, rp, N, E);

  // ---- GNN pipeline, both branches batched ----
  spmm_kernel<1><<<dim3(sg, 2), blk, 0, stream>>>(rp, edges, w1_h, 0, bc[0], x_h, XS, N);

  for (int layer = 0; ; ++layer) {
    int zdim = (layer == 3) ? 1 : 2;
    score_kernel<<<dim3(gx, 2, zdim), blk, SCORE_LDS, stream>>>(
        x_h, XS, l1w_h, l2w_h, l1b, l2b, w3f, sacc, (size_t)N,
        (layer == 3) ? nullptr : Wt_h[layer], tb_h, N);
    if (layer == 3) break;
    if (layer < 2)
      spmm_kernel<1><<<dim3(sg, 2), blk, 0, stream>>>(rp, edges, tb_h, XS, bc[layer + 1], x_h, XS, N);
    else
      spmm_kernel<0><<<dim3(sg, 2), blk, 0, stream>>>(rp, edges, tb_h, XS, bc[3], x_h, XS, N);
  }
  final_kernel<<<(N + 255) / 256, blk, 0, stream>>>(sacc, sacc + N, l3b, d_out, N, dt);
}

// Round 14
// 577.309 us; speedup vs baseline: 1.1602x; 1.1130x over previous
//
#include <hip/hip_runtime.h>
#include <hip/hip_bf16.h>

#define NN 50000
#define HH 128
#define H2 256
#define EE 800000
#define NBUCK 196          // ceil(NN/256)
#define BINCH 4096         // edges per bin-pass block
#define MT 96              // score/xW M-tile
#define XST 136            // staged-x LDS row stride (halves)

typedef _Float16 half8 __attribute__((ext_vector_type(8)));
typedef _Float16 half4v __attribute__((ext_vector_type(4)));
typedef float float4v __attribute__((ext_vector_type(4)));

__device__ __forceinline__ float bf2f(unsigned short u) {
  union { unsigned int i; float f; } v; v.i = ((unsigned int)u) << 16; return v.f;
}
__device__ __forceinline__ unsigned short f2bf(float f) {
  union { float f; unsigned int i; } v; v.f = f;
  unsigned int x = v.i;
  unsigned int r = x + 0x7fffu + ((x >> 16) & 1u);   // RNE
  return (unsigned short)(r >> 16);
}

// ---------------- dtype detection (fp32 vs bf16 float tensors) ----------------
__global__ void detect_kernel(const unsigned int* __restrict__ val, int* __restrict__ dt) {
  unsigned int w = val[threadIdx.x];
  unsigned short u = (unsigned short)(w & 0xffff);
  int expf = (u >> 7) & 0xff;
  bool match = ((u >> 15) == 0) && expf >= 0x5A && expf <= 0x7E;
  unsigned long long m = __ballot(match);
  if (threadIdx.x == 0) dt[0] = (__popcll(m) >= 48) ? 1 : 0;
}

// ---------------- merged parameter conversion (14 segments, 1 launch) ----------------
// mode 0: f32 out. mode 1: f16 out.
// mode 3: f16 MFMA-fragment-swizzle from row-major [n,k] input (kd=K).
// mode 4: f16 MFMA-fragment-swizzle from [k,n] input (128x128, kd=128).
// Fragment layout: off = (ks*(NC/16) + (n>>4))*512 + ((k>>3&3)*16 + (n&15))*8 + (k&7)
#define NSEG 14
struct ConvSegs {
  const void* s[NSEG];
  void* d[NSEG];
  int n[NSEG];
  int mode[NSEG];
  int kd[NSEG];
  int bstart[NSEG + 1];
};

__global__ __launch_bounds__(256) void convall_kernel(ConvSegs cs, const int* __restrict__ dt) {
  int b = blockIdx.x;
  int seg = 0;
  while (b >= cs.bstart[seg + 1]) ++seg;
  int i = (b - cs.bstart[seg]) * 256 + threadIdx.x;
  if (i >= cs.n[seg]) return;
  float f = dt[0] ? bf2f(((const unsigned short*)cs.s[seg])[i])
                  : ((const float*)cs.s[seg])[i];
  int m = cs.mode[seg];
  if (m == 0) { ((float*)cs.d[seg])[i] = f; return; }
  if (m == 1) { ((_Float16*)cs.d[seg])[i] = (_Float16)f; return; }
  int K = cs.kd[seg];
  int n, k;
  if (m == 3) { n = i / K; k = i - n * K; }
  else        { k = i >> 7; n = i & 127; }
  int NC16 = (cs.n[seg] / K) >> 4;
  int off = ((k >> 5) * NC16 + (n >> 4)) * 512 + (((k >> 3) & 3) * 16 + (n & 15)) * 8 + (k & 7);
  ((_Float16*)cs.d[seg])[off] = (_Float16)f;
}

// ---------------- CSR build: bucket-local ----------------
__global__ __launch_bounds__(256) void bincount_kernel(
    const int* __restrict__ r0, const int* __restrict__ r1,
    int* __restrict__ bcnt, int E) {
  int br = blockIdx.y;
  const int* rows = br ? r1 : r0;
  __shared__ int cnt_s[NBUCK];
  int t = threadIdx.x;
  for (int i = t; i < NBUCK; i += 256) cnt_s[i] = 0;
  __syncthreads();
  int e0 = blockIdx.x * BINCH;
  #pragma unroll
  for (int i = 0; i < 16; ++i) {
    int e = e0 + i * 256 + t;
    if (e < E) atomicAdd(&cnt_s[rows[e] >> 8], 1);
  }
  __syncthreads();
  for (int i = t; i < NBUCK; i += 256) {
    int c = cnt_s[i];
    if (c) atomicAdd(&bcnt[br * NBUCK + i], c);
  }
}

__global__ __launch_bounds__(256) void bscan_kernel(const int* __restrict__ bcnt,
                                                    int* __restrict__ bbase,
                                                    int* __restrict__ gcur) {
  int br = blockIdx.y, t = threadIdx.x;
  __shared__ int s[256];
  int v = (t < NBUCK) ? bcnt[br * NBUCK + t] : 0;
  s[t] = v;
  __syncthreads();
  for (int off = 1; off < 256; off <<= 1) {
    int u = (t >= off) ? s[t - off] : 0;
    __syncthreads();
    s[t] += u;
    __syncthreads();
  }
  int ex = s[t] - v;
  if (t < NBUCK) { bbase[br * NBUCK + t] = ex; gcur[br * NBUCK + t] = ex; }
}

__global__ __launch_bounds__(256) void bin_kernel(
    const int* __restrict__ r0, const int* __restrict__ r1,
    const int* __restrict__ c0, const int* __restrict__ c1,
    const void* __restrict__ v0, const void* __restrict__ v1,
    int* __restrict__ gcur, int2* __restrict__ binned, int E, const int* __restrict__ dt) {
  int br = blockIdx.y;
  const int* rows = br ? r1 : r0;
  const int* cols = br ? c1 : c0;
  const void* vals = br ? v1 : v0;
  int2* bout = binned + (size_t)br * EE;
  int* cur = gcur + br * NBUCK;
  __shared__ int cnt_s[NBUCK];
  __shared__ int base_s[NBUCK];
  int t = threadIdx.x;
  for (int i = t; i < NBUCK; i += 256) cnt_s[i] = 0;
  __syncthreads();
  int e0 = blockIdx.x * BINCH;
  int row[16], col[16], vb[16];
  int cnt = 0;
  bool isb = dt[0] != 0;
  #pragma unroll
  for (int i = 0; i < 16; ++i) {
    int e = e0 + i * 256 + t;
    if (e < E) {
      row[cnt] = rows[e];
      col[cnt] = cols[e];
      float v = isb ? bf2f(((const unsigned short*)vals)[e]) : ((const float*)vals)[e];
      vb[cnt] = __float_as_int(v);
      atomicAdd(&cnt_s[row[cnt] >> 8], 1);
      ++cnt;
    }
  }
  __syncthreads();
  for (int i = t; i < NBUCK; i += 256) {
    int c = cnt_s[i];
    base_s[i] = c ? atomicAdd(&cur[i], c) : 0;
    cnt_s[i] = 0;
  }
  __syncthreads();
  for (int i = 0; i < cnt; ++i) {
    int b = row[i] >> 8;
    int off = atomicAdd(&cnt_s[b], 1);
    bout[base_s[b] + off] = make_int2((row[i] << 16) | col[i], vb[i]);
  }
}

__global__ __launch_bounds__(256) void bucket_kernel(
    const int* __restrict__ bbase, const int2* __restrict__ binned,
    int2* __restrict__ edges, int* __restrict__ rp, int N, int E) {
  int br = blockIdx.y, b = blockIdx.x, t = threadIdx.x;
  const int2* bin = binned + (size_t)br * EE;
  int2* eo = edges + (size_t)br * EE;
  int* r = rp + br * (NN + 1);
  __shared__ int cur[256];
  __shared__ int s[256];
  int base = bbase[br * NBUCK + b];
  int end  = (b + 1 < NBUCK) ? bbase[br * NBUCK + b + 1] : E;
  cur[t] = 0;
  __syncthreads();
  for (int i = base + t; i < end; i += 256)
    atomicAdd(&cur[(((unsigned)bin[i].x) >> 16) & 255], 1);
  __syncthreads();
  int v = cur[t];
  s[t] = v;
  __syncthreads();
  for (int off = 1; off < 256; off <<= 1) {
    int u = (t >= off) ? s[t - off] : 0;
    __syncthreads();
    s[t] += u;
    __syncthreads();
  }
  int ex = base + s[t] - v;
  int row = b * 256 + t;
  if (row < N) r[row] = ex;
  if (b == 0 && t == 0) r[N] = E;
  cur[t] = ex;
  __syncthreads();
  for (int i = base + t; i < end; i += 256) {
    int2 e = bin[i];
    int rl = (((unsigned)e.x) >> 16) & 255;
    int p = atomicAdd(&cur[rl], 1);
    eo[p] = make_int2(e.x & 0xffff, e.y);
  }
}

// ---------------- SpMM: 16-lane group (fp16x8 = 16B/lane) per row, unroll 4 ----------------
// (R9 structure: measured 61.5 us; do not "improve")
template<int DO_L2>
__global__ __launch_bounds__(256) void spmm_kernel(
    const int* __restrict__ rp, const int2* __restrict__ edges,
    const _Float16* __restrict__ src, size_t sstride, const float* __restrict__ bias,
    _Float16* __restrict__ dst, size_t dstride, int N)
{
  int br = blockIdx.y;
  rp += br * (NN + 1);
  edges += (size_t)br * EE;
  src += br * sstride;
  dst += br * dstride;
  int g = threadIdx.x >> 4;
  int l = threadIdx.x & 15;
  int r = blockIdx.x * 16 + g;
  if (r >= N) return;
  int kb = rp[r], ke = rp[r + 1];
  float a0[8] = {0,0,0,0,0,0,0,0}, a1[8] = {0,0,0,0,0,0,0,0};
  float a2[8] = {0,0,0,0,0,0,0,0}, a3[8] = {0,0,0,0,0,0,0,0};
  int k = kb;
  for (; k + 3 < ke; k += 4) {
    int2 e0 = edges[k], e1 = edges[k + 1], e2 = edges[k + 2], e3 = edges[k + 3];
    half8 s0 = *(const half8*)(src + (size_t)e0.x * HH + l * 8);
    half8 s1 = *(const half8*)(src + (size_t)e1.x * HH + l * 8);
    half8 s2 = *(const half8*)(src + (size_t)e2.x * HH + l * 8);
    half8 s3 = *(const half8*)(src + (size_t)e3.x * HH + l * 8);
    float v0 = __int_as_float(e0.y), v1 = __int_as_float(e1.y);
    float v2 = __int_as_float(e2.y), v3 = __int_as_float(e3.y);
    #pragma unroll
    for (int j = 0; j < 8; ++j) {
      a0[j] = fmaf(v0, (float)s0[j], a0[j]);
      a1[j] = fmaf(v1, (float)s1[j], a1[j]);
      a2[j] = fmaf(v2, (float)s2[j], a2[j]);
      a3[j] = fmaf(v3, (float)s3[j], a3[j]);
    }
  }
  for (; k < ke; ++k) {
    int2 e0 = edges[k];
    half8 s0 = *(const half8*)(src + (size_t)e0.x * HH + l * 8);
    float v0 = __int_as_float(e0.y);
    #pragma unroll
    for (int j = 0; j < 8; ++j) a0[j] = fmaf(v0, (float)s0[j], a0[j]);
  }
  float x[8];
  #pragma unroll
  for (int j = 0; j < 8; ++j)
    x[j] = fmaxf((a0[j] + a1[j]) + (a2[j] + a3[j]) + bias[l * 8 + j], 0.f);
  if (DO_L2) {
    float ss = 0.f;
    #pragma unroll
    for (int j = 0; j < 8; ++j) ss += x[j] * x[j];
    #pragma unroll
    for (int m = 1; m < 16; m <<= 1) ss += __shfl_xor(ss, m, 64);
    float sc = 1.f / fmaxf(sqrtf(ss), 1e-12f);
    #pragma unroll
    for (int j = 0; j < 8; ++j) x[j] *= sc;
  }
  half8 hv;
  #pragma unroll
  for (int j = 0; j < 8; ++j) hv[j] = (_Float16)x[j];
  *(half8*)&dst[(size_t)r * HH + l * 8] = hv;
}

// ---------------- fused score MLP (z=0) + xW GEMM (z=1), 96-row tiles ----------------
// x staged to LDS; w1/w2/wt in fragment-major layout (coalesced 1KB wave loads).
__global__ __launch_bounds__(256, 2) void score_kernel(
    const _Float16* __restrict__ x, size_t xs,
    const _Float16* __restrict__ w1, const _Float16* __restrict__ w2,
    const float* __restrict__ b1v, const float* __restrict__ b2v, const float* __restrict__ w3v,
    float* __restrict__ S, size_t ss,
    const _Float16* __restrict__ wt, _Float16* __restrict__ tb, int M)
{
  constexpr int HS = H2 + 8;                 // 264 halves
  extern __shared__ _Float16 smem[];         // [MT*XST staged x][MT*HS h1]
  _Float16* xls = smem;
  _Float16* h1s = smem + MT * XST;
  int br = blockIdx.y;
  x += br * xs;
  const int lane = threadIdx.x & 63, w = threadIdx.x >> 6;
  const int lm = lane & 15, lq = lane >> 4;
  const int m0 = blockIdx.x * MT;

  // ---- stage x tile (MT x 128 fp16) into LDS ----
  {
    const uint4* xg = (const uint4*)(x + (size_t)m0 * HH);
    #pragma unroll
    for (int i = 0; i < 6; ++i) {
      int idx = threadIdx.x + i * 256;
      int row = idx >> 4, cq = idx & 15;
      uint4 v = xg[(size_t)row * 16 + cq];
      *(uint4*)&xls[row * XST + cq * 8] = v;
    }
  }
  __syncthreads();

  if (blockIdx.z == 1) {
    // ---- xW path: 96 x 128, wave w: m-half (w&1)*48, n-half (w>>1)*64; wt frag-major (HH/16=8 ntiles)
    tb += br * xs;
    const int wm = (w & 1) * 48, wn = (w >> 1) * 64;
    float4v acc[3][4];
    #pragma unroll
    for (int i = 0; i < 3; ++i)
      #pragma unroll
      for (int j = 0; j < 4; ++j) acc[i][j] = (float4v){0.f, 0.f, 0.f, 0.f};
    #pragma unroll
    for (int k0 = 0; k0 < HH; k0 += 32) {
      half8 ah[3], bh[4];
      #pragma unroll
      for (int mt = 0; mt < 3; ++mt)
        ah[mt] = *(const half8*)&xls[(wm + mt * 16 + lm) * XST + k0 + lq * 8];
      #pragma unroll
      for (int nt = 0; nt < 4; ++nt)
        bh[nt] = *(const half8*)(wt + (((k0 >> 5) * 8) + (wn >> 4) + nt) * 512 + lane * 8);
      #pragma unroll
      for (int mt = 0; mt < 3; ++mt)
        #pragma unroll
        for (int nt = 0; nt < 4; ++nt)
          acc[mt][nt] = __builtin_amdgcn_mfma_f32_16x16x32_f16(ah[mt], bh[nt], acc[mt][nt], 0, 0, 0);
    }
    #pragma unroll
    for (int mt = 0; mt < 3; ++mt)
      #pragma unroll
      for (int r = 0; r < 4; ++r) {
        int row = m0 + wm + mt * 16 + lq * 4 + r;
        if (row >= M) continue;
        #pragma unroll
        for (int nt = 0; nt < 4; ++nt)
          tb[(size_t)row * HH + wn + nt * 16 + lm] = (_Float16)acc[mt][nt][r];
      }
    return;
  }

  // ---- score path: each wave owns 64 n-cols, all 96 rows (6x4 acc) ----
  S += br * ss;
  const int wn = w * 64;
  {
    // w1 frag-major: K=HH, ntiles = H2/16 = 16
    float4v acc[6][4];
    #pragma unroll
    for (int i = 0; i < 6; ++i)
      #pragma unroll
      for (int j = 0; j < 4; ++j) acc[i][j] = (float4v){0.f, 0.f, 0.f, 0.f};
    #pragma unroll
    for (int k0 = 0; k0 < HH; k0 += 32) {
      half8 ah[6], bh[4];
      #pragma unroll
      for (int mt = 0; mt < 6; ++mt)
        ah[mt] = *(const half8*)&xls[(mt * 16 + lm) * XST + k0 + lq * 8];
      #pragma unroll
      for (int nt = 0; nt < 4; ++nt)
        bh[nt] = *(const half8*)(w1 + (((k0 >> 5) * 16) + (wn >> 4) + nt) * 512 + lane * 8);
      #pragma unroll
      for (int mt = 0; mt < 6; ++mt)
        #pragma unroll
        for (int nt = 0; nt < 4; ++nt)
          acc[mt][nt] = __builtin_amdgcn_mfma_f32_16x16x32_f16(ah[mt], bh[nt], acc[mt][nt], 0, 0, 0);
    }
    float bv[4];
    #pragma unroll
    for (int nt = 0; nt < 4; ++nt) bv[nt] = b1v[wn + nt * 16 + lm];
    #pragma unroll
    for (int mt = 0; mt < 6; ++mt)
      #pragma unroll
      for (int r = 0; r < 4; ++r) {
        int rowl = mt * 16 + lq * 4 + r;
        #pragma unroll
        for (int nt = 0; nt < 4; ++nt)
          h1s[rowl * HS + wn + nt * 16 + lm] = (_Float16)fmaxf(acc[mt][nt][r] + bv[nt], 0.f);
      }
  }
  __syncthreads();
  {
    // w2 frag-major: K=H2, ntiles = 16
    float4v acc[6][4];
    #pragma unroll
    for (int i = 0; i < 6; ++i)
      #pragma unroll
      for (int j = 0; j < 4; ++j) acc[i][j] = (float4v){0.f, 0.f, 0.f, 0.f};
    #pragma unroll
    for (int k0 = 0; k0 < H2; k0 += 32) {
      half8 ah[6], bh[4];
      #pragma unroll
      for (int mt = 0; mt < 6; ++mt)
        ah[mt] = *(const half8*)&h1s[(mt * 16 + lm) * HS + k0 + lq * 8];
      #pragma unroll
      for (int nt = 0; nt < 4; ++nt)
        bh[nt] = *(const half8*)(w2 + (((k0 >> 5) * 16) + (wn >> 4) + nt) * 512 + lane * 8);
      #pragma unroll
      for (int mt = 0; mt < 6; ++mt)
        #pragma unroll
        for (int nt = 0; nt < 4; ++nt)
          acc[mt][nt] = __builtin_amdgcn_mfma_f32_16x16x32_f16(ah[mt], bh[nt], acc[mt][nt], 0, 0, 0);
    }
    float bv[4], wv[4];
    #pragma unroll
    for (int nt = 0; nt < 4; ++nt) {
      int col = wn + nt * 16 + lm;
      bv[nt] = b2v[col]; wv[nt] = w3v[col];
    }
    #pragma unroll
    for (int mt = 0; mt < 6; ++mt)
      #pragma unroll
      for (int r = 0; r < 4; ++r) {
        float p = 0.f;
        #pragma unroll
        for (int nt = 0; nt < 4; ++nt)
          p += fmaxf(acc[mt][nt][r] + bv[nt], 0.f) * wv[nt];
        p += __shfl_xor(p, 1, 64);
        p += __shfl_xor(p, 2, 64);
        p += __shfl_xor(p, 4, 64);
        p += __shfl_xor(p, 8, 64);
        if (lm == 0) {
          int row = m0 + mt * 16 + lq * 4 + r;
          if (row < M) atomicAdd(&S[row], p);
        }
      }
  }
}

__global__ void final_kernel(const float* __restrict__ s_in, const float* __restrict__ s_out,
                             const float* __restrict__ b3, void* __restrict__ out, int N,
                             const int* __restrict__ dt) {
  int i = blockIdx.x * 256 + threadIdx.x;
  if (i >= N) return;
  float b = 4.f * b3[0];
  float v = (s_in[i] + b) * (s_out[i] + b);
  if (dt[0]) ((unsigned short*)out)[i] = f2bf(v);
  else       ((float*)out)[i] = v;
}

extern "C" void kernel_launch(void* const* d_in, const int* in_sizes, int n_in,
                              void* d_out, int out_size, void* d_ws, size_t ws_size,
                              hipStream_t stream) {
  const int N = NN, E = EE;

  char* ws = (char*)d_ws;
  size_t o = 0;
  auto alloc = [&](size_t bytes) -> void* {
    void* p = ws + o;
    o = (o + bytes + 255) & ~(size_t)255;
    return p;
  };

  int* dt = (int*)alloc(16);
  float* bc[4]; float* l1b; float* l2b; float* w3f; float* l3b;
  for (int i = 0; i < 4; ++i) bc[i] = (float*)alloc(HH * 4);
  l1b = (float*)alloc(H2 * 4);
  l2b = (float*)alloc(H2 * 4);
  w3f = (float*)alloc(H2 * 4);
  l3b = (float*)alloc(4);
  _Float16* l1w_h = (_Float16*)alloc(H2 * HH * 2);
  _Float16* l2w_h = (_Float16*)alloc(H2 * H2 * 2);
  _Float16* Wt_h[3];
  for (int i = 0; i < 3; ++i) Wt_h[i] = (_Float16*)alloc(HH * HH * 2);
  _Float16* w1_h = (_Float16*)alloc((size_t)N * HH * 2);

  const int NP = N + 128;
  const size_t XS = (size_t)NP * HH;
  int* rp    = (int*)alloc(2 * (size_t)(N + 1) * 4);
  int* bcnt  = (int*)alloc(2 * NBUCK * 4);
  int* bbase = (int*)alloc(2 * NBUCK * 4);
  int* gcur  = (int*)alloc(2 * NBUCK * 4);
  int2* binned = (int2*)alloc(2 * (size_t)E * 8);
  int2* edges  = (int2*)alloc(2 * (size_t)E * 8);
  _Float16* x_h  = (_Float16*)alloc(2 * XS * 2);
  _Float16* tb_h = (_Float16*)alloc(2 * XS * 2);
  float* sacc = (float*)alloc(2 * (size_t)N * 4);

  dim3 blk(256);
  detect_kernel<<<1, 64, 0, stream>>>((const unsigned int*)d_in[2], dt);

  // merged conversions (w1/w2/wt in fragment-major layout)
  ConvSegs cs;
  const void* srcs[NSEG] = {d_in[7], d_in[9], d_in[11], d_in[13], d_in[15], d_in[17],
                            d_in[18], d_in[19], d_in[14], d_in[16], d_in[8], d_in[10],
                            d_in[12], d_in[6]};
  void* dsts[NSEG] = {bc[0], bc[1], bc[2], bc[3], l1b, l2b, w3f, l3b,
                      l1w_h, l2w_h, Wt_h[0], Wt_h[1], Wt_h[2], w1_h};
  int ns[NSEG] = {HH, HH, HH, HH, H2, H2, H2, 1,
                  H2 * HH, H2 * H2, HH * HH, HH * HH, HH * HH, N * HH};
  int ms[NSEG] = {0, 0, 0, 0, 0, 0, 0, 0, 3, 3, 4, 4, 4, 1};
  int ks[NSEG] = {0, 0, 0, 0, 0, 0, 0, 0, HH, H2, HH, HH, HH, 0};
  int btot = 0;
  for (int i = 0; i < NSEG; ++i) {
    cs.s[i] = srcs[i]; cs.d[i] = dsts[i]; cs.n[i] = ns[i]; cs.mode[i] = ms[i]; cs.kd[i] = ks[i];
    cs.bstart[i] = btot;
    btot += (ns[i] + 255) / 256;
  }
  cs.bstart[NSEG] = btot;
  convall_kernel<<<btot, blk, 0, stream>>>(cs, dt);

  hipMemsetAsync(sacc, 0, 2 * (size_t)N * 4, stream);
  hipMemsetAsync(bcnt, 0, 2 * NBUCK * 4, stream);

  int gx  = (N + MT - 1) / MT;
  int sg  = (N + 15) / 16;
  int bg  = (E + BINCH - 1) / BINCH;
  const size_t SCORE_LDS = (MT * XST + MT * (H2 + 8)) * sizeof(_Float16);   // 76800 B

  // ---- CSR build, both branches in parallel ----
  bincount_kernel<<<dim3(bg, 2), blk, 0, stream>>>((const int*)d_in[0], (const int*)d_in[3], bcnt, E);
  bscan_kernel<<<dim3(1, 2), blk, 0, stream>>>(bcnt, bbase, gcur);
  bin_kernel<<<dim3(bg, 2), blk, 0, stream>>>(
      (const int*)d_in[0], (const int*)d_in[3], (const int*)d_in[1], (const int*)d_in[4],
      d_in[2], d_in[5], gcur, binned, E, dt);
  bucket_kernel<<<dim3(NBUCK, 2), blk, 0, stream>>>(bbase, binned, edges, rp, N, E);

  // ---- GNN pipeline, both branches batched ----
  spmm_kernel<1><<<dim3(sg, 2), blk, 0, stream>>>(rp, edges, w1_h, 0, bc[0], x_h, XS, N);

  for (int layer = 0; ; ++layer) {
    int zdim = (layer == 3) ? 1 : 2;
    score_kernel<<<dim3(gx, 2, zdim), blk, SCORE_LDS, stream>>>(
        x_h, XS, l1w_h, l2w_h, l1b, l2b, w3f, sacc, (size_t)N,
        (layer == 3) ? nullptr : Wt_h[layer], tb_h, N);
    if (layer == 3) break;
    if (layer < 2)
      spmm_kernel<1><<<dim3(sg, 2), blk, 0, stream>>>(rp, edges, tb_h, XS, bc[layer + 1], x_h, XS, N);
    else
      spmm_kernel<0><<<dim3(sg, 2), blk, 0, stream>>>(rp, edges, tb_h, XS, bc[3], x_h, XS, N);
  }
  final_kernel<<<(N + 255) / 256, blk, 0, stream>>>(sacc, sacc + N, l3b, d_out, N, dt);
}